// Round 2
// baseline (135.180 us; speedup 1.0000x reference)
//
#include <hip/hip_runtime.h>

#define NUM_HEADS 16
#define HEAD_DIM  128
#define SEQ       2048
#define KT_STRIDE 8192   // bf16 elems per k-tile group in KF/VF (16 chunks * 512)

typedef __attribute__((ext_vector_type(8))) unsigned short us8;
typedef __attribute__((ext_vector_type(8))) __bf16 bf16x8;
typedef __attribute__((ext_vector_type(4))) float f32x4;
typedef __attribute__((ext_vector_type(16))) float f32x16;
typedef __attribute__((ext_vector_type(4))) unsigned u32x4;
typedef __attribute__((ext_vector_type(2))) unsigned u32x2;

static __device__ inline unsigned short f2bf(float x) {   // RNE
    union { float f; unsigned u; } v; v.f = x;
    unsigned r = v.u + 0x7FFFu + ((v.u >> 16) & 1u);
    return (unsigned short)(r >> 16);
}
static __device__ inline unsigned pk2bf(float a, float b) {
    return (unsigned)f2bf(a) | ((unsigned)f2bf(b) << 16);
}
static __device__ inline float fast_exp2(float x) {
#if __has_builtin(__builtin_amdgcn_exp2f)
    return __builtin_amdgcn_exp2f(x);
#else
    return exp2f(x);
#endif
}
// pack hi16(clo) into lo half, hi16(chi) into hi half (both truncated bf16)
static __device__ inline unsigned pack_hi(unsigned clo, unsigned chi) {
#if __has_builtin(__builtin_amdgcn_perm)
    return __builtin_amdgcn_perm(chi, clo, 0x07060302u);
#else
    return (clo >> 16) | (chi & 0xffff0000u);
#endif
}
static __device__ inline f32x16 mfma32(us8 a, us8 b, f32x16 c) {
    return __builtin_amdgcn_mfma_f32_32x32x16_bf16(
        __builtin_bit_cast(bf16x8, a), __builtin_bit_cast(bf16x8, b), c, 0, 0, 0);
}

// ---------- pre-pass: write K and V^T in exact 32x32x16 A-fragment order ----------
// 512 blocks (2 which x 2 kh x 32 kt x 4 kvh), 32 rows each -> 2 blocks/CU
__global__ __launch_bounds__(256)
void prep_frag(const float* __restrict__ K, const float* __restrict__ V,
               unsigned short* __restrict__ KF, unsigned short* __restrict__ VF)
{
    const int bx  = (int)blockIdx.x, t = (int)threadIdx.x;
    const int which = bx & 1, khb = (bx >> 1) & 1, kt = (bx >> 2) & 31, kvh = bx >> 7;
    __shared__ __align__(16) float Ls[32][132];

    const float* src = (which ? V : K) + ((size_t)kvh * SEQ + kt * 64 + khb * 32) * HEAD_DIM;
    #pragma unroll
    for (int i = 0; i < 4; ++i) {
        const int idx = t + i * 256;
        const int r = idx >> 5, c4 = idx & 31;
        *(float4*)&Ls[r][c4 * 4] = *(const float4*)(src + (size_t)r * HEAD_DIM + c4 * 4);
    }
    __syncthreads();

    if (!which) {  // K fragments
        #pragma unroll
        for (int i = 0; i < 2; ++i) {
            const int c = t + i * 256;              // 0..511
            const int lane = c & 63, ds = (c >> 6) & 3, mat = (c >> 8) & 1;
            const int H = lane >> 5;
            const int row = lane & 31;              // local row within our 32
            const int dim = mat * 64 + ds * 16 + H * 8;
            u32x4 pk;
            #pragma unroll
            for (int jj = 0; jj < 4; ++jj)
                pk[jj] = pk2bf(Ls[row][dim + 2*jj], Ls[row][dim + 2*jj + 1]);
            *(us8*)(KF + ((size_t)(kvh * 32 + kt) * 16 + khb * 8 + mat * 4 + ds) * 512 + lane * 8)
                = __builtin_bit_cast(us8, pk);
        }
    } else {       // V^T fragments
        #pragma unroll
        for (int i = 0; i < 2; ++i) {
            const int c = t + i * 256;
            const int lane = c & 63, db = (c >> 6) & 3, ks = (c >> 8) & 1;
            const int H = lane >> 5;
            const int s0 = ks * 16 + H * 8;         // local row within our 32
            const int d  = db * 32 + (lane & 31);
            u32x4 pk;
            #pragma unroll
            for (int jj = 0; jj < 4; ++jj)
                pk[jj] = pk2bf(Ls[s0 + 2*jj][d], Ls[s0 + 2*jj + 1][d]);
            *(us8*)(VF + ((size_t)(kvh * 32 + kt) * 16 + khb * 8 + ks * 4 + db) * 512 + lane * 8)
                = __builtin_bit_cast(us8, pk);
        }
    }
}

// ---------- main: 1024 single-qtile blocks, 3 blocks/CU, permlane P-swap ----------
__global__ __launch_bounds__(256, 3)
void diff_attn_mfma11(const float* __restrict__ Q,
                      const unsigned short* __restrict__ KF,
                      const unsigned short* __restrict__ VF,
                      float* __restrict__ Out)
{
    __shared__ float cb[2][32][136];   // epilogue-only combine buffer
    __shared__ float rsb[2][2][32];

    const int t   = (int)threadIdx.x;
    const int wv  = t >> 6;
    const int ln  = t & 63;
    const int mat = wv >> 1;        // 0: softmax1 (dims 0..63), 1: softmax2 (64..127)
    const int kh  = wv & 1;         // k-half of the 64-k tile
    const int q   = ln & 31;        // q-col
    const int H   = ln >> 5;

    // grid 1024 = 16 h x 64 q-tiles; longest q-tiles dispatched first
    const int bx  = (int)blockIdx.x;
    const int h   = bx & 15;
    const int qt  = 63 - (bx >> 4);           // 63..0 (descending work)
    const int nkt = (qt >> 1) + 1;            // 32..1
    const int kvh = h >> 2;

    const unsigned short* kfb = KF + ((size_t)kvh * 32 * 16 + kh * 8 + mat * 4) * 512 + ln * 8;
    const unsigned short* vfb = VF + ((size_t)kvh * 32 * 16 + kh * 8) * 512 + ln * 8;

    const float qscale = 0.125f * 1.44269504088896340736f;  // 1/8 * log2(e)

    us8 qhi[4];
    auto loadQ = [&](int q0c) {
        const float* qr = Q + ((size_t)h * SEQ + q0c + q) * HEAD_DIM + mat * 64;
        #pragma unroll
        for (int ds = 0; ds < 4; ++ds) {
            const int d0 = ds * 16 + H * 8;
            float x[8];
            *(float4*)&x[0] = *(const float4*)(qr + d0);
            *(float4*)&x[4] = *(const float4*)(qr + d0 + 4);
            us8 hi8;
            #pragma unroll
            for (int j = 0; j < 8; ++j) hi8[j] = f2bf(x[j] * qscale);
            qhi[ds] = hi8;
        }
    };

    f32x16 o[4];                   // O^T: dim = db*32+(r&3)+8*(r>>2)+4H, q-col = q
    f32x4  rsv;                    // row-sum partials

    auto epilogue = [&](int q0c) {
        __syncthreads();
        float rsc = (rsv[0] + rsv[1]) + (rsv[2] + rsv[3]);
        rsc += __shfl_xor(rsc, 32, 64);
        if (ln < 32) rsb[mat][kh][ln] = rsc;
        if (kh == 1) {
            #pragma unroll
            for (int db = 0; db < 4; ++db)
                #pragma unroll
                for (int i = 0; i < 4; ++i) {
                    float4 v = { o[db][i*4+0], o[db][i*4+1], o[db][i*4+2], o[db][i*4+3] };
                    *(float4*)&cb[mat][q][db * 32 + 8 * i + 4 * H] = v;
                }
        }
        __syncthreads();
        if (kh == 0) {
            const float l = rsb[mat][0][q] + rsb[mat][1][q];
            const float a = mat ? (0.16f / l) : (0.2f / l);
            #pragma unroll
            for (int db = 0; db < 4; ++db)
                #pragma unroll
                for (int i = 0; i < 4; ++i) {
                    float4 v = *(float4*)&cb[mat][q][db * 32 + 8 * i + 4 * H];
                    o[db][i*4+0] = (o[db][i*4+0] + v.x) * a;
                    o[db][i*4+1] = (o[db][i*4+1] + v.y) * a;
                    o[db][i*4+2] = (o[db][i*4+2] + v.z) * a;
                    o[db][i*4+3] = (o[db][i*4+3] + v.w) * a;
                }
            if (mat == 1) {
                #pragma unroll
                for (int db = 0; db < 4; ++db)
                    #pragma unroll
                    for (int i = 0; i < 4; ++i) {
                        float4 v = { o[db][i*4+0], o[db][i*4+1], o[db][i*4+2], o[db][i*4+3] };
                        *(float4*)&cb[1][q][db * 32 + 8 * i + 4 * H] = v;
                    }
            }
        }
        __syncthreads();
        if (wv == 0) {
            float* ob = Out + ((size_t)h * SEQ + q0c + q) * HEAD_DIM;
            #pragma unroll
            for (int db = 0; db < 4; ++db)
                #pragma unroll
                for (int i = 0; i < 4; ++i) {
                    float4 v = *(float4*)&cb[1][q][db * 32 + 8 * i + 4 * H];
                    float4 r;
                    r.x = o[db][i*4+0] - v.x;
                    r.y = o[db][i*4+1] - v.y;
                    r.z = o[db][i*4+2] - v.z;
                    r.w = o[db][i*4+3] - v.w;
                    *(float4*)(ob + db * 32 + 8 * i + 4 * H) = r;
                }
        }
    };

    // one causal segment; K prefetched one tile ahead (double-buffered, 2x unroll
    // avoids reg ping-pong movs); scores computed in-iteration (funds 3-wave occupancy)
    auto run_seg = [&](int q0c, int nseg) {
        us8 kaA[4], kaB[4];

        auto body = [&](int j, us8 (&kaIn)[4], us8 (&kaOut)[4]) {
            // V loads first: maximize distance to PV use
            us8 va[8];
            {
                const unsigned short* vb = vfb + (size_t)j * KT_STRIDE;
                #pragma unroll
                for (int c = 0; c < 8; ++c) va[c] = *(const us8*)(vb + c * 512);
            }
            // prefetch next K tile
            if (j + 1 < nseg) {
                const unsigned short* kb = kfb + (size_t)(j + 1) * KT_STRIDE;
                #pragma unroll
                for (int ds = 0; ds < 4; ++ds) kaOut[ds] = *(const us8*)(kb + ds * 512);
            }
            // scores for this tile
            f32x16 s = (f32x16)0.f;
            #pragma unroll
            for (int ds = 0; ds < 4; ++ds) s = mfma32(kaIn[ds], qhi[ds], s);

            // exp2 (+ causal mask on diagonal tile only)
            unsigned c[16];
            if (j == nseg - 1) {
                const int kg0 = j * 64 + kh * 32 + 4 * H;
                const int qg  = q0c + q;
                #pragma unroll
                for (int r = 0; r < 16; ++r) {
                    const int kg = kg0 + (r & 3) + ((r >> 2) << 3);
                    float e = (kg <= qg) ? fast_exp2(s[r]) : 0.f;
                    c[r] = __builtin_bit_cast(unsigned, e);
                }
            } else {
                #pragma unroll
                for (int r = 0; r < 16; ++r)
                    c[r] = __builtin_bit_cast(unsigned, fast_exp2(s[r]));
            }
            // pack to bf16 pairs (truncation), accumulate denominator from QUANTIZED P,
            // C-frag -> B-frag via permlane32_swap (one instr yields both output words)
            #pragma unroll
            for (int ks = 0; ks < 2; ++ks) {
                const unsigned pA = pack_hi(c[8*ks+0], c[8*ks+1]);
                const unsigned pB = pack_hi(c[8*ks+2], c[8*ks+3]);
                const unsigned pC = pack_hi(c[8*ks+4], c[8*ks+5]);
                const unsigned pD = pack_hi(c[8*ks+6], c[8*ks+7]);
                rsv[0] += __builtin_bit_cast(float, pA << 16);
                rsv[1] += __builtin_bit_cast(float, pA & 0xffff0000u);
                rsv[2] += __builtin_bit_cast(float, pB << 16);
                rsv[3] += __builtin_bit_cast(float, pB & 0xffff0000u);
                rsv[0] += __builtin_bit_cast(float, pC << 16);
                rsv[1] += __builtin_bit_cast(float, pC & 0xffff0000u);
                rsv[2] += __builtin_bit_cast(float, pD << 16);
                rsv[3] += __builtin_bit_cast(float, pD & 0xffff0000u);
                u32x4 bw;
#if __has_builtin(__builtin_amdgcn_permlane32_swap)
                // swap(pA,pC): ret0 = {pA[0:32]|pC[0:32]}, ret1 = {pA[32:64]|pC[32:64]}
                u32x2 r02 = __builtin_amdgcn_permlane32_swap(pA, pC, false, false);
                u32x2 r13 = __builtin_amdgcn_permlane32_swap(pB, pD, false, false);
                bw[0] = r02[0]; bw[1] = r13[0]; bw[2] = r02[1]; bw[3] = r13[1];
#else
                const unsigned x1 = H ? pA : pC;
                const unsigned x2 = H ? pB : pD;
                const unsigned t1 = (unsigned)__shfl_xor((int)x1, 32, 64);
                const unsigned t2 = (unsigned)__shfl_xor((int)x2, 32, 64);
                bw[0] = H ? t1 : pA;
                bw[1] = H ? t2 : pB;
                bw[2] = H ? pC : t1;
                bw[3] = H ? pD : t2;
#endif
                const us8 bp = __builtin_bit_cast(us8, bw);
                #pragma unroll
                for (int db = 0; db < 4; ++db)
                    o[db] = mfma32(va[ks * 4 + db], bp, o[db]);
            }
        };

        #pragma unroll
        for (int ds = 0; ds < 4; ++ds) kaA[ds] = *(const us8*)(kfb + ds * 512);

        int j = 0;
        for (; j + 2 <= nseg; j += 2) {
            body(j,     kaA, kaB);
            body(j + 1, kaB, kaA);
        }
        if (j < nseg) body(j, kaA, kaB);
    };

    loadQ(qt * 32);
    #pragma unroll
    for (int i = 0; i < 4; ++i) o[i] = (f32x16)0.f;
    rsv = (f32x4)0.f;
    run_seg(qt * 32, nkt);
    epilogue(qt * 32);
}

extern "C" void kernel_launch(void* const* d_in, const int* in_sizes, int n_in,
                              void* d_out, int out_size, void* d_ws, size_t ws_size,
                              hipStream_t stream) {
    const float* Q = (const float*)d_in[0];
    const float* K = (const float*)d_in[1];
    const float* V = (const float*)d_in[2];
    float* Out = (float*)d_out;

    unsigned short* KF = (unsigned short*)d_ws;             // 2 MB
    unsigned short* VF = KF + (size_t)4 * SEQ * HEAD_DIM;   // 2 MB

    prep_frag<<<512, 256, 0, stream>>>(K, V, KF, VF);
    diff_attn_mfma11<<<1024, 256, 0, stream>>>(Q, KF, VF, Out);
}

// Round 3
// 112.324 us; speedup vs baseline: 1.2035x; 1.2035x over previous
//
#include <hip/hip_runtime.h>

#define NUM_HEADS 16
#define HEAD_DIM  128
#define SEQ       2048
#define KT_STRIDE 8192   // bf16 elems per k-tile group in KF/VF (16 chunks * 512)

typedef __attribute__((ext_vector_type(8))) unsigned short us8;
typedef __attribute__((ext_vector_type(8))) __bf16 bf16x8;
typedef __attribute__((ext_vector_type(4))) float f32x4;
typedef __attribute__((ext_vector_type(16))) float f32x16;
typedef __attribute__((ext_vector_type(4))) unsigned u32x4;
typedef __attribute__((ext_vector_type(2))) unsigned u32x2;

static __device__ inline unsigned short f2bf(float x) {   // RNE
    union { float f; unsigned u; } v; v.f = x;
    unsigned r = v.u + 0x7FFFu + ((v.u >> 16) & 1u);
    return (unsigned short)(r >> 16);
}
static __device__ inline unsigned pk2bf(float a, float b) {
    return (unsigned)f2bf(a) | ((unsigned)f2bf(b) << 16);
}
static __device__ inline float fast_exp2(float x) {
#if __has_builtin(__builtin_amdgcn_exp2f)
    return __builtin_amdgcn_exp2f(x);
#else
    return exp2f(x);
#endif
}
// pack hi16(clo) into lo half, hi16(chi) into hi half (both truncated bf16)
static __device__ inline unsigned pack_hi(unsigned clo, unsigned chi) {
#if __has_builtin(__builtin_amdgcn_perm)
    return __builtin_amdgcn_perm(chi, clo, 0x07060302u);
#else
    return (clo >> 16) | (chi & 0xffff0000u);
#endif
}
static __device__ inline f32x16 mfma32(us8 a, us8 b, f32x16 c) {
    return __builtin_amdgcn_mfma_f32_32x32x16_bf16(
        __builtin_bit_cast(bf16x8, a), __builtin_bit_cast(bf16x8, b), c, 0, 0, 0);
}

// ---------- pre-pass: write K and V^T in exact 32x32x16 A-fragment order ----------
// 512 blocks (2 which x 2 kh x 32 kt x 4 kvh), 32 rows each -> 2 blocks/CU
__global__ __launch_bounds__(256)
void prep_frag(const float* __restrict__ K, const float* __restrict__ V,
               unsigned short* __restrict__ KF, unsigned short* __restrict__ VF)
{
    const int bx  = (int)blockIdx.x, t = (int)threadIdx.x;
    const int which = bx & 1, khb = (bx >> 1) & 1, kt = (bx >> 2) & 31, kvh = bx >> 7;
    __shared__ __align__(16) float Ls[32][132];

    const float* src = (which ? V : K) + ((size_t)kvh * SEQ + kt * 64 + khb * 32) * HEAD_DIM;
    #pragma unroll
    for (int i = 0; i < 4; ++i) {
        const int idx = t + i * 256;
        const int r = idx >> 5, c4 = idx & 31;
        *(float4*)&Ls[r][c4 * 4] = *(const float4*)(src + (size_t)r * HEAD_DIM + c4 * 4);
    }
    __syncthreads();

    if (!which) {  // K fragments
        #pragma unroll
        for (int i = 0; i < 2; ++i) {
            const int c = t + i * 256;              // 0..511
            const int lane = c & 63, ds = (c >> 6) & 3, mat = (c >> 8) & 1;
            const int H = lane >> 5;
            const int row = lane & 31;              // local row within our 32
            const int dim = mat * 64 + ds * 16 + H * 8;
            u32x4 pk;
            #pragma unroll
            for (int jj = 0; jj < 4; ++jj)
                pk[jj] = pk2bf(Ls[row][dim + 2*jj], Ls[row][dim + 2*jj + 1]);
            *(us8*)(KF + ((size_t)(kvh * 32 + kt) * 16 + khb * 8 + mat * 4 + ds) * 512 + lane * 8)
                = __builtin_bit_cast(us8, pk);
        }
    } else {       // V^T fragments
        #pragma unroll
        for (int i = 0; i < 2; ++i) {
            const int c = t + i * 256;
            const int lane = c & 63, db = (c >> 6) & 3, ks = (c >> 8) & 1;
            const int H = lane >> 5;
            const int s0 = ks * 16 + H * 8;         // local row within our 32
            const int d  = db * 32 + (lane & 31);
            u32x4 pk;
            #pragma unroll
            for (int jj = 0; jj < 4; ++jj)
                pk[jj] = pk2bf(Ls[s0 + 2*jj][d], Ls[s0 + 2*jj + 1][d]);
            *(us8*)(VF + ((size_t)(kvh * 32 + kt) * 16 + khb * 8 + ks * 4 + db) * 512 + lane * 8)
                = __builtin_bit_cast(us8, pk);
        }
    }
}

// ---------- main: 1024 single-qtile blocks, true 3 blocks/CU (register-dieted) ----------
// Register budget @ 3 waves/SIMD: 168 unified - 64 AGPR (o[4]) = 104 arch.
// Diet: single score reg (s rewritten at body end = pipeline w/o ping-pong pair),
// single-buffered ka (loaded at body start, used at body end), va split in halves.
__global__ __launch_bounds__(256, 3)
void diff_attn_mfma12(const float* __restrict__ Q,
                      const unsigned short* __restrict__ KF,
                      const unsigned short* __restrict__ VF,
                      float* __restrict__ Out)
{
    __shared__ float cb[2][32][136];   // epilogue-only combine buffer
    __shared__ float rsb[2][2][32];

    const int t   = (int)threadIdx.x;
    const int wv  = t >> 6;
    const int ln  = t & 63;
    const int mat = wv >> 1;        // 0: softmax1 (dims 0..63), 1: softmax2 (64..127)
    const int kh  = wv & 1;         // k-half of the 64-k tile
    const int q   = ln & 31;        // q-col
    const int H   = ln >> 5;

    // grid 1024 = 16 h x 64 q-tiles; longest q-tiles dispatched first
    const int bx  = (int)blockIdx.x;
    const int h   = bx & 15;
    const int qt  = 63 - (bx >> 4);           // 63..0 (descending work)
    const int nkt = (qt >> 1) + 1;            // 32..1
    const int kvh = h >> 2;

    const unsigned short* kfb = KF + ((size_t)kvh * 32 * 16 + kh * 8 + mat * 4) * 512 + ln * 8;
    const unsigned short* vfb = VF + ((size_t)kvh * 32 * 16 + kh * 8) * 512 + ln * 8;

    const float qscale = 0.125f * 1.44269504088896340736f;  // 1/8 * log2(e)
    const int q0c = qt * 32;

    us8 qhi[4];
    {
        const float* qr = Q + ((size_t)h * SEQ + q0c + q) * HEAD_DIM + mat * 64;
        #pragma unroll
        for (int ds = 0; ds < 4; ++ds) {
            const int d0 = ds * 16 + H * 8;
            float x[8];
            *(float4*)&x[0] = *(const float4*)(qr + d0);
            *(float4*)&x[4] = *(const float4*)(qr + d0 + 4);
            us8 hi8;
            #pragma unroll
            for (int j = 0; j < 8; ++j) hi8[j] = f2bf(x[j] * qscale);
            qhi[ds] = hi8;
        }
    }

    f32x16 o[4];                   // O^T: dim = db*32+(r&3)+8*(r>>2)+4H, q-col = q
    #pragma unroll
    for (int i = 0; i < 4; ++i) o[i] = (f32x16)0.f;
    f32x4 rsv = (f32x4)0.f;        // row-sum partials

    // ---- main loop ----
    us8 ka[4];
    f32x16 s;

    // prologue: scores for tile 0
    #pragma unroll
    for (int ds = 0; ds < 4; ++ds) ka[ds] = *(const us8*)(kfb + ds * 512);
    s = (f32x16)0.f;
    #pragma unroll
    for (int ds = 0; ds < 4; ++ds) s = mfma32(ka[ds], qhi[ds], s);

    // body: consumes s=S(j); loads ka<-K(j+1) at start; rewrites s=S(j+1) at end.
    auto body = [&](int j, bool last) {
        const unsigned short* vb = vfb + (size_t)j * KT_STRIDE;
        us8 va0[4];
        #pragma unroll
        for (int c4 = 0; c4 < 4; ++c4) va0[c4] = *(const us8*)(vb + c4 * 512);
        if (!last) {
            const unsigned short* kb = kfb + (size_t)(j + 1) * KT_STRIDE;
            #pragma unroll
            for (int ds = 0; ds < 4; ++ds) ka[ds] = *(const us8*)(kb + ds * 512);
        }

        // ---- ks = 0: exp2 rows 0..7 ----
        unsigned c0[8];
        if (last) {
            const int kg0 = j * 64 + kh * 32 + 4 * H;
            const int qg  = q0c + q;
            #pragma unroll
            for (int r = 0; r < 8; ++r) {
                const int kg = kg0 + (r & 3) + ((r >> 2) << 3);
                float e = (kg <= qg) ? fast_exp2(s[r]) : 0.f;
                c0[r] = __builtin_bit_cast(unsigned, e);
            }
        } else {
            #pragma unroll
            for (int r = 0; r < 8; ++r)
                c0[r] = __builtin_bit_cast(unsigned, fast_exp2(s[r]));
        }
        unsigned pA = pack_hi(c0[0], c0[1]);
        unsigned pB = pack_hi(c0[2], c0[3]);
        unsigned pC = pack_hi(c0[4], c0[5]);
        unsigned pD = pack_hi(c0[6], c0[7]);
        rsv[0] += __builtin_bit_cast(float, pA << 16);
        rsv[1] += __builtin_bit_cast(float, pA & 0xffff0000u);
        rsv[2] += __builtin_bit_cast(float, pB << 16);
        rsv[3] += __builtin_bit_cast(float, pB & 0xffff0000u);
        rsv[0] += __builtin_bit_cast(float, pC << 16);
        rsv[1] += __builtin_bit_cast(float, pC & 0xffff0000u);
        rsv[2] += __builtin_bit_cast(float, pD << 16);
        rsv[3] += __builtin_bit_cast(float, pD & 0xffff0000u);
        u32x4 bw;
#if __has_builtin(__builtin_amdgcn_permlane32_swap)
        {
            u32x2 r02 = __builtin_amdgcn_permlane32_swap(pA, pC, false, false);
            u32x2 r13 = __builtin_amdgcn_permlane32_swap(pB, pD, false, false);
            bw[0] = r02[0]; bw[1] = r13[0]; bw[2] = r02[1]; bw[3] = r13[1];
        }
#else
        {
            const unsigned x1 = H ? pA : pC;
            const unsigned x2 = H ? pB : pD;
            const unsigned t1 = (unsigned)__shfl_xor((int)x1, 32, 64);
            const unsigned t2 = (unsigned)__shfl_xor((int)x2, 32, 64);
            bw[0] = H ? t1 : pA;
            bw[1] = H ? t2 : pB;
            bw[2] = H ? pC : t1;
            bw[3] = H ? pD : t2;
        }
#endif
        us8 bp = __builtin_bit_cast(us8, bw);

        // issue second V half now: covered by ks0 PV MFMAs + ks1 exp2/pack
        us8 va1[4];
        #pragma unroll
        for (int c4 = 0; c4 < 4; ++c4) va1[c4] = *(const us8*)(vb + (4 + c4) * 512);

        #pragma unroll
        for (int db = 0; db < 4; ++db) o[db] = mfma32(va0[db], bp, o[db]);

        // ---- ks = 1: exp2 rows 8..15 ----
        if (last) {
            const int kg0 = j * 64 + kh * 32 + 4 * H;
            const int qg  = q0c + q;
            #pragma unroll
            for (int r = 8; r < 16; ++r) {
                const int kg = kg0 + (r & 3) + ((r >> 2) << 3);
                float e = (kg <= qg) ? fast_exp2(s[r]) : 0.f;
                c0[r - 8] = __builtin_bit_cast(unsigned, e);
            }
        } else {
            #pragma unroll
            for (int r = 8; r < 16; ++r)
                c0[r - 8] = __builtin_bit_cast(unsigned, fast_exp2(s[r]));
        }
        pA = pack_hi(c0[0], c0[1]);
        pB = pack_hi(c0[2], c0[3]);
        pC = pack_hi(c0[4], c0[5]);
        pD = pack_hi(c0[6], c0[7]);
        rsv[0] += __builtin_bit_cast(float, pA << 16);
        rsv[1] += __builtin_bit_cast(float, pA & 0xffff0000u);
        rsv[2] += __builtin_bit_cast(float, pB << 16);
        rsv[3] += __builtin_bit_cast(float, pB & 0xffff0000u);
        rsv[0] += __builtin_bit_cast(float, pC << 16);
        rsv[1] += __builtin_bit_cast(float, pC & 0xffff0000u);
        rsv[2] += __builtin_bit_cast(float, pD << 16);
        rsv[3] += __builtin_bit_cast(float, pD & 0xffff0000u);
#if __has_builtin(__builtin_amdgcn_permlane32_swap)
        {
            u32x2 r02 = __builtin_amdgcn_permlane32_swap(pA, pC, false, false);
            u32x2 r13 = __builtin_amdgcn_permlane32_swap(pB, pD, false, false);
            bw[0] = r02[0]; bw[1] = r13[0]; bw[2] = r02[1]; bw[3] = r13[1];
        }
#else
        {
            const unsigned x1 = H ? pA : pC;
            const unsigned x2 = H ? pB : pD;
            const unsigned t1 = (unsigned)__shfl_xor((int)x1, 32, 64);
            const unsigned t2 = (unsigned)__shfl_xor((int)x2, 32, 64);
            bw[0] = H ? t1 : pA;
            bw[1] = H ? t2 : pB;
            bw[2] = H ? pC : t1;
            bw[3] = H ? pD : t2;
        }
#endif
        bp = __builtin_bit_cast(us8, bw);
        #pragma unroll
        for (int db = 0; db < 4; ++db) o[db] = mfma32(va1[db], bp, o[db]);

        // scores for next tile (ka loads have had the whole body to land)
        if (!last) {
            s = (f32x16)0.f;
            #pragma unroll
            for (int ds = 0; ds < 4; ++ds) s = mfma32(ka[ds], qhi[ds], s);
        }
    };

    for (int j = 0; j < nkt - 1; ++j) body(j, false);
    body(nkt - 1, true);

    // ---- epilogue ----
    __syncthreads();
    {
        float rsc = (rsv[0] + rsv[1]) + (rsv[2] + rsv[3]);
        rsc += __shfl_xor(rsc, 32, 64);
        if (ln < 32) rsb[mat][kh][ln] = rsc;
    }
    if (kh == 1) {
        #pragma unroll
        for (int db = 0; db < 4; ++db)
            #pragma unroll
            for (int i = 0; i < 4; ++i) {
                float4 v = { o[db][i*4+0], o[db][i*4+1], o[db][i*4+2], o[db][i*4+3] };
                *(float4*)&cb[mat][q][db * 32 + 8 * i + 4 * H] = v;
            }
    }
    __syncthreads();
    if (kh == 0) {
        const float l = rsb[mat][0][q] + rsb[mat][1][q];
        const float a = mat ? (0.16f / l) : (0.2f / l);
        #pragma unroll
        for (int db = 0; db < 4; ++db)
            #pragma unroll
            for (int i = 0; i < 4; ++i) {
                float4 v = *(float4*)&cb[mat][q][db * 32 + 8 * i + 4 * H];
                o[db][i*4+0] = (o[db][i*4+0] + v.x) * a;
                o[db][i*4+1] = (o[db][i*4+1] + v.y) * a;
                o[db][i*4+2] = (o[db][i*4+2] + v.z) * a;
                o[db][i*4+3] = (o[db][i*4+3] + v.w) * a;
            }
        if (mat == 1) {
            #pragma unroll
            for (int db = 0; db < 4; ++db)
                #pragma unroll
                for (int i = 0; i < 4; ++i) {
                    float4 v = { o[db][i*4+0], o[db][i*4+1], o[db][i*4+2], o[db][i*4+3] };
                    *(float4*)&cb[1][q][db * 32 + 8 * i + 4 * H] = v;
                }
        }
    }
    __syncthreads();
    if (wv == 0) {
        float* ob = Out + ((size_t)h * SEQ + q0c + q) * HEAD_DIM;
        #pragma unroll
        for (int db = 0; db < 4; ++db)
            #pragma unroll
            for (int i = 0; i < 4; ++i) {
                float4 v = *(float4*)&cb[1][q][db * 32 + 8 * i + 4 * H];
                float4 r;
                r.x = o[db][i*4+0] - v.x;
                r.y = o[db][i*4+1] - v.y;
                r.z = o[db][i*4+2] - v.z;
                r.w = o[db][i*4+3] - v.w;
                *(float4*)(ob + db * 32 + 8 * i + 4 * H) = r;
            }
    }
}

extern "C" void kernel_launch(void* const* d_in, const int* in_sizes, int n_in,
                              void* d_out, int out_size, void* d_ws, size_t ws_size,
                              hipStream_t stream) {
    const float* Q = (const float*)d_in[0];
    const float* K = (const float*)d_in[1];
    const float* V = (const float*)d_in[2];
    float* Out = (float*)d_out;

    unsigned short* KF = (unsigned short*)d_ws;             // 2 MB
    unsigned short* VF = KF + (size_t)4 * SEQ * HEAD_DIM;   // 2 MB

    prep_frag<<<512, 256, 0, stream>>>(K, V, KF, VF);
    diff_attn_mfma12<<<1024, 256, 0, stream>>>(Q, KF, VF, Out);
}